// Round 3
// baseline (405.550 us; speedup 1.0000x reference)
//
#include <hip/hip_runtime.h>
#include <hip/hip_bf16.h>

// 2-layer LSTM (H=32, T=512, I=1) + FC(1) + ReLU, fused.
// MFMA 16x16x32 bf16, NBW=2 batches/wave -> 2048 waves = 2 waves/SIMD.
// Full elementwise split: lane (m=l>>4, q=(l&15)>>1, s=l&1) owns hidden unit
// u=8m+q of batch s (64 distinct updates/wave/step, zero redundancy).
// Gate extraction: 8-slot cndmask select (A[2tau+(q>>2)][q&3], masks in SGPR).
// h reassembly to B-frag: ds_swizzle(xor2) pair-pack + cvt_pk + 4 ds_bpermute.
// Activation scales pre-folded into weight rows; MFMA C-in = const zero.

typedef __attribute__((ext_vector_type(8))) short bf16x8;
typedef __attribute__((ext_vector_type(4))) float f32x4;
typedef __attribute__((ext_vector_type(4))) int   i32x4;

#define HID 32
#define SEQ 512
#define NBW 2
#define L2E 1.4426950408889634f

static __device__ __forceinline__ float fexp2(float x){ return __builtin_amdgcn_exp2f(x); }
static __device__ __forceinline__ float frcp (float x){ return __builtin_amdgcn_rcpf(x); }
static __device__ __forceinline__ short f2bf(float f){
  unsigned u = __builtin_bit_cast(unsigned, f);
  u = (u + 0x7fffu + ((u >> 16) & 1u)) >> 16;
  return (short)u;
}

// 8-way select: gate (tau, u=8m+q) lives at A[2*tau + (q>>2)][q&3].
// b1=(q&1), b2=(q&2), b4=(q&4) hoisted to SGPR-pair masks by the compiler.
#define SEL8(t) ({                                        \
  float e01_ = b1 ? A[2*(t)][1]   : A[2*(t)][0];          \
  float e23_ = b1 ? A[2*(t)][3]   : A[2*(t)][2];          \
  float o01_ = b1 ? A[2*(t)+1][1] : A[2*(t)+1][0];        \
  float o23_ = b1 ? A[2*(t)+1][3] : A[2*(t)+1][2];        \
  float ee_  = b2 ? e23_ : e01_;                          \
  float oo_  = b2 ? o23_ : o01_;                          \
  b4 ? oo_ : ee_; })

__global__ __launch_bounds__(64, 2) void lstm2_fused_kernel(
    const float* __restrict__ x,
    const float* __restrict__ Wih0, const float* __restrict__ Whh0,
    const float* __restrict__ bih0, const float* __restrict__ bhh0,
    const float* __restrict__ Wih1, const float* __restrict__ Whh1,
    const float* __restrict__ bih1, const float* __restrict__ bhh1,
    const float* __restrict__ Wfc, const float* __restrict__ bfc,
    float* __restrict__ out)
{
  const int l   = threadIdx.x;
  const int m   = l >> 4;          // A/B fragment k-group
  const int col = l & 15;          // MFMA N col
  const int q   = col >> 1;        // unit selector: owns unit u = 8m+q
  const int s   = col & 1;         // batch slot
  const int batch = blockIdx.x * NBW + s;
  const bool b1 = (q & 1) != 0, b2 = (q & 2) != 0, b4 = (q & 4) != 0;

  // ---- weight fragments (A operands), rows pre-scaled by activation scale:
  //      i,f,o rows: -log2e (sigmoid);  g rows: +2*log2e (tanh)
  bf16x8 whh0f[8], wih1f[8], whh1f[8];
  #pragma unroll
  for (int c = 0; c < 8; ++c) {
    const int tau = c >> 1, kh = c & 1;
    const float sc = (tau == 2) ? (2.0f * L2E) : (-L2E);
    const int ga = tau * 32 + ((col >> 2) << 3) + (kh << 2) + (col & 3);
    #pragma unroll
    for (int j = 0; j < 8; ++j) {
      const int k = m * 8 + j;
      whh0f[c][j] = f2bf(sc * Whh0[ga * HID + k]);
      wih1f[c][j] = f2bf(sc * Wih1[ga * HID + k]);
      whh1f[c][j] = f2bf(sc * Whh1[ga * HID + k]);
    }
  }

  // ---- per-lane activation constants for its single unit u = 8m+q
  const int u = 8 * m + q;
  float c0x[4], w0x[4], c1x[4];
  #pragma unroll
  for (int tau = 0; tau < 4; ++tau) {
    const float sc = (tau == 2) ? (2.0f * L2E) : (-L2E);
    const int g = tau * 32 + u;
    c0x[tau] = sc * (bih0[g] + bhh0[g]);
    w0x[tau] = sc * Wih0[g];
    c1x[tau] = sc * (bih1[g] + bhh1[g]);
  }
  const float wfc  = Wfc[u];
  const float bfc0 = bfc[0];

  // ---- bpermute source addresses for B-frag gather:
  //      dword J (k = 8m+2J, 8m+2J+1) of batch s comes from lane 16m+4J+s
  int ba[4];
  #pragma unroll
  for (int J = 0; J < 4; ++J) ba[J] = 4 * (16 * m + 4 * J + s);

  const f32x4 z4 = {0.f, 0.f, 0.f, 0.f};
  bf16x8 h0f = {}, h1f = {};
  float c0v = 0.f, c1v = 0.f, h1v = 0.f;

  const float* xb = x + (size_t)batch * SEQ;

  for (int t4 = 0; t4 < SEQ / 4; ++t4) {
    const float4 xv = *reinterpret_cast<const float4*>(xb + t4 * 4);
    #pragma unroll
    for (int uu = 0; uu < 4; ++uu) {
      const float xt = (uu == 0) ? xv.x : (uu == 1) ? xv.y : (uu == 2) ? xv.z : xv.w;

      // ---------- layer 0: D = Whh0*h0 ----------
      f32x4 A[8];
      #pragma unroll
      for (int c = 0; c < 8; ++c)
        A[c] = __builtin_amdgcn_mfma_f32_16x16x32_bf16(whh0f[c], h0f, z4, 0, 0, 0);

      {
        const float gi = SEL8(0) + fmaf(w0x[0], xt, c0x[0]);
        const float gf = SEL8(1) + fmaf(w0x[1], xt, c0x[1]);
        const float gg = SEL8(2) + fmaf(w0x[2], xt, c0x[2]);
        const float go = SEL8(3) + fmaf(w0x[3], xt, c0x[3]);
        const float iv = frcp(1.f + fexp2(gi));                   // sigmoid
        const float fv = frcp(1.f + fexp2(gf));
        const float gv = fmaf(frcp(1.f + fexp2(gg)), -2.f, 1.f);  // tanh
        const float ov = frcp(1.f + fexp2(go));
        c0v = fmaf(fv, c0v, iv * gv);
        const float th = fmaf(frcp(1.f + fexp2(c0v * (2.f * L2E))), -2.f, 1.f);
        const float h0v = ov * th;

        // pair-pack (even unit lo, odd unit hi) then gather B-frag dwords
        const int hb = __builtin_bit_cast(int, h0v);
        const int hpb = __builtin_amdgcn_ds_swizzle(hb, 0x081F);  // lane ^ 2
        const float hp = __builtin_bit_cast(float, hpb);
        const float lo = b1 ? hp : h0v;
        const float hi = b1 ? h0v : hp;
        int pk;
        asm("v_cvt_pk_bf16_f32 %0, %1, %2" : "=v"(pk) : "v"(lo), "v"(hi));
        i32x4 hd;
        #pragma unroll
        for (int J = 0; J < 4; ++J) hd[J] = __builtin_amdgcn_ds_bpermute(ba[J], pk);
        h0f = __builtin_bit_cast(bf16x8, hd);
      }

      // ---------- layer 1: D = Wih1*h0_new + Whh1*h1_prev ----------
      #pragma unroll
      for (int c = 0; c < 8; ++c)
        A[c] = __builtin_amdgcn_mfma_f32_16x16x32_bf16(wih1f[c], h0f, z4, 0, 0, 0);
      #pragma unroll
      for (int c = 0; c < 8; ++c)
        A[c] = __builtin_amdgcn_mfma_f32_16x16x32_bf16(whh1f[c], h1f, A[c], 0, 0, 0);

      {
        const float gi = SEL8(0) + c1x[0];
        const float gf = SEL8(1) + c1x[1];
        const float gg = SEL8(2) + c1x[2];
        const float go = SEL8(3) + c1x[3];
        const float iv = frcp(1.f + fexp2(gi));
        const float fv = frcp(1.f + fexp2(gf));
        const float gv = fmaf(frcp(1.f + fexp2(gg)), -2.f, 1.f);
        const float ov = frcp(1.f + fexp2(go));
        c1v = fmaf(fv, c1v, iv * gv);
        const float th = fmaf(frcp(1.f + fexp2(c1v * (2.f * L2E))), -2.f, 1.f);
        h1v = ov * th;

        const int hb = __builtin_bit_cast(int, h1v);
        const int hpb = __builtin_amdgcn_ds_swizzle(hb, 0x081F);
        const float hp = __builtin_bit_cast(float, hpb);
        const float lo = b1 ? hp : h1v;
        const float hi = b1 ? h1v : hp;
        int pk;
        asm("v_cvt_pk_bf16_f32 %0, %1, %2" : "=v"(pk) : "v"(lo), "v"(hi));
        i32x4 hd;
        #pragma unroll
        for (int J = 0; J < 4; ++J) hd[J] = __builtin_amdgcn_ds_bpermute(ba[J], pk);
        h1f = __builtin_bit_cast(bf16x8, hd);
      }
    }
  }

  // ---- FC + ReLU: out[b] = relu(sum_u h1[u]*Wfc[u] + bfc) ----
  // lane parity == s; reduce over bits 1..5, lanes 0/1 hold batch 0/1 sums
  float part = h1v * wfc;
  part += __shfl_xor(part, 2);
  part += __shfl_xor(part, 4);
  part += __shfl_xor(part, 8);
  part += __shfl_xor(part, 16);
  part += __shfl_xor(part, 32);
  if (l < 2) {
    const float o = part + bfc0;
    out[blockIdx.x * NBW + l] = o > 0.f ? o : 0.f;
  }
}

extern "C" void kernel_launch(void* const* d_in, const int* in_sizes, int n_in,
                              void* d_out, int out_size, void* d_ws, size_t ws_size,
                              hipStream_t stream) {
  const float* x    = (const float*)d_in[0];
  const float* Wih0 = (const float*)d_in[1];
  const float* Whh0 = (const float*)d_in[2];
  const float* bih0 = (const float*)d_in[3];
  const float* bhh0 = (const float*)d_in[4];
  const float* Wih1 = (const float*)d_in[5];
  const float* Whh1 = (const float*)d_in[6];
  const float* bih1 = (const float*)d_in[7];
  const float* bhh1 = (const float*)d_in[8];
  const float* Wfc  = (const float*)d_in[9];
  const float* bfc  = (const float*)d_in[10];

  const int B = 4096;
  const int grid = B / NBW;   // 2048 single-wave blocks -> 2 waves/SIMD
  lstm2_fused_kernel<<<grid, 64, 0, stream>>>(
      x, Wih0, Whh0, bih0, bhh0, Wih1, Whh1, bih1, bhh1, Wfc, bfc,
      (float*)d_out);
}

// Round 4
// 303.674 us; speedup vs baseline: 1.3355x; 1.3355x over previous
//
#include <hip/hip_runtime.h>
#include <hip/hip_bf16.h>

// 2-layer LSTM (H=32, T=512, I=1) + FC(1) + ReLU, fused, layer-pipelined.
// Block = 128 threads = 2 waves: wave 0 runs layer 0, wave 1 runs layer 1
// one step behind, h0 handed over as a ready B-fragment via LDS (double
// buffered, one __syncthreads per step). Per-wave structure is round-2's
// proven NBW=4 form: MFMA 16x16x32 bf16, lane (m,q,s) owns units 8m+2q+{0,1}
// of batch s; 3-cndmask gate select; cvt_pk + 4 ds_swizzle h reassembly.
// Activation scales pre-folded into weights; MFMA C-in = const zero.

typedef __attribute__((ext_vector_type(8))) short bf16x8;
typedef __attribute__((ext_vector_type(4))) float f32x4;
typedef __attribute__((ext_vector_type(4))) int   i32x4;

#define HID 32
#define SEQ 512
#define NBW 4
#define L2E 1.4426950408889634f

static __device__ __forceinline__ float fexp2(float x){ return __builtin_amdgcn_exp2f(x); }
static __device__ __forceinline__ float frcp (float x){ return __builtin_amdgcn_rcpf(x); }
static __device__ __forceinline__ short f2bf(float f){
  unsigned u = __builtin_bit_cast(unsigned, f);
  u = (u + 0x7fffu + ((u >> 16) & 1u)) >> 16;
  return (short)u;
}

// gate (tau, unit 8m+2q+jj) lives at A[2*tau + (q>>1)][2*(q&1) + jj]
#define SEL(Atab, tau, jj) \
  ( khb ? ( rb ? Atab[2*(tau)+1][2+(jj)] : Atab[2*(tau)+1][(jj)] ) \
        : ( rb ? Atab[2*(tau)  ][2+(jj)] : Atab[2*(tau)  ][(jj)] ) )

__global__ __launch_bounds__(128, 2) void lstm2_pipe_kernel(
    const float* __restrict__ x,
    const float* __restrict__ Wih0, const float* __restrict__ Whh0,
    const float* __restrict__ bih0, const float* __restrict__ bhh0,
    const float* __restrict__ Wih1, const float* __restrict__ Whh1,
    const float* __restrict__ bih1, const float* __restrict__ bhh1,
    const float* __restrict__ Wfc, const float* __restrict__ bfc,
    float* __restrict__ out)
{
  const int tid = threadIdx.x;
  const int w   = tid >> 6;        // 0: layer-0 producer, 1: layer-1 consumer
  const int l   = tid & 63;
  const int m   = l >> 4;          // A/B fragment k-group
  const int col = l & 15;          // MFMA N col
  const int q   = col >> 2;        // replication group -> units 8m+2q+{0,1}
  const int s   = col & 3;         // batch slot
  const int batch = blockIdx.x * NBW + s;
  const bool khb = ((q >> 1) & 1) != 0;
  const bool rb  = (q & 1) != 0;

  __shared__ i32x4 hbuf[2][64];    // double-buffered h0 B-fragment, 2 KiB

  // ---- weight fragments (A operands), rows pre-scaled by activation scale:
  //      i,f,o rows: -log2e (sigmoid);  g rows: +2*log2e (tanh)
  bf16x8 wf0[8], wf1[8];   // w==0: wf0=Whh0 (wf1 unused); w==1: wf0=Wih1, wf1=Whh1
  #pragma unroll
  for (int c = 0; c < 8; ++c) {
    const int tau = c >> 1, kh = c & 1;
    const float sc = (tau == 2) ? (2.0f * L2E) : (-L2E);
    const int ga = tau * 32 + (q << 3) + (kh << 2) + s;   // A-row = col packing
    if (w == 0) {
      #pragma unroll
      for (int j = 0; j < 8; ++j)
        wf0[c][j] = f2bf(sc * Whh0[ga * HID + (m * 8 + j)]);
    } else {
      #pragma unroll
      for (int j = 0; j < 8; ++j) {
        wf0[c][j] = f2bf(sc * Wih1[ga * HID + (m * 8 + j)]);
        wf1[c][j] = f2bf(sc * Whh1[ga * HID + (m * 8 + j)]);
      }
    }
  }

  // ---- per-lane activation constants for units u = 8m+2q+jj
  float cx[4][2], wx[4][2];
  #pragma unroll
  for (int tau = 0; tau < 4; ++tau) {
    const float sc = (tau == 2) ? (2.0f * L2E) : (-L2E);
    #pragma unroll
    for (int jj = 0; jj < 2; ++jj) {
      const int g = tau * 32 + 8 * m + 2 * q + jj;
      if (w == 0) {
        cx[tau][jj] = sc * (bih0[g] + bhh0[g]);
        wx[tau][jj] = sc * Wih0[g];
      } else {
        cx[tau][jj] = sc * (bih1[g] + bhh1[g]);
        wx[tau][jj] = 0.f;
      }
    }
  }
  float wfcA = 0.f, wfcB = 0.f;
  if (w == 1) { wfcA = Wfc[8 * m + 2 * q]; wfcB = Wfc[8 * m + 2 * q + 1]; }

  const f32x4 z4 = {0.f, 0.f, 0.f, 0.f};
  bf16x8 hf = {};                 // w0: own h0 frag; w1: own h1 frag
  float cv[2] = {0.f, 0.f};
  float hn0 = 0.f, hn1 = 0.f;

  const float* xb = x + (size_t)batch * SEQ;

  for (int t4 = 0; t4 < SEQ / 4; ++t4) {
    float4 xv = {0.f, 0.f, 0.f, 0.f};
    if (w == 0) xv = *reinterpret_cast<const float4*>(xb + t4 * 4);
    #pragma unroll
    for (int uu = 0; uu < 4; ++uu) {
      if (w == 0) {
        // ---------- layer 0: D = Whh0*h0 ----------
        const float xt = (uu == 0) ? xv.x : (uu == 1) ? xv.y : (uu == 2) ? xv.z : xv.w;
        f32x4 A[8];
        #pragma unroll
        for (int c = 0; c < 8; ++c)
          A[c] = __builtin_amdgcn_mfma_f32_16x16x32_bf16(wf0[c], hf, z4, 0, 0, 0);
        #pragma unroll
        for (int jj = 0; jj < 2; ++jj) {
          const float gi = SEL(A, 0, jj) + fmaf(wx[0][jj], xt, cx[0][jj]);
          const float gf = SEL(A, 1, jj) + fmaf(wx[1][jj], xt, cx[1][jj]);
          const float gg = SEL(A, 2, jj) + fmaf(wx[2][jj], xt, cx[2][jj]);
          const float go = SEL(A, 3, jj) + fmaf(wx[3][jj], xt, cx[3][jj]);
          const float iv = frcp(1.f + fexp2(gi));                   // sigmoid
          const float fv = frcp(1.f + fexp2(gf));
          const float gv = fmaf(frcp(1.f + fexp2(gg)), -2.f, 1.f);  // tanh
          const float ov = frcp(1.f + fexp2(go));
          cv[jj] = fmaf(fv, cv[jj], iv * gv);
          const float th = fmaf(frcp(1.f + fexp2(cv[jj] * (2.f * L2E))), -2.f, 1.f);
          const float hn = ov * th;
          if (jj == 0) hn0 = hn; else hn1 = hn;
        }
        int pk;
        asm("v_cvt_pk_bf16_f32 %0, %1, %2" : "=v"(pk) : "v"(hn0), "v"(hn1));
        i32x4 hd;
        hd[0] = __builtin_amdgcn_ds_swizzle(pk, 0x013);
        hd[1] = __builtin_amdgcn_ds_swizzle(pk, 0x093);
        hd[2] = __builtin_amdgcn_ds_swizzle(pk, 0x113);
        hd[3] = __builtin_amdgcn_ds_swizzle(pk, 0x193);
        hf = __builtin_bit_cast(bf16x8, hd);
        hbuf[uu & 1][l] = hd;       // publish B-fragment for wave 1
      }
      __syncthreads();
      if (w == 1) {
        // ---------- layer 1: D = Wih1*h0(t) + Whh1*h1(t-1) ----------
        const i32x4 hd = hbuf[uu & 1][l];
        const bf16x8 h0f = __builtin_bit_cast(bf16x8, hd);
        f32x4 A[8];
        #pragma unroll
        for (int c = 0; c < 8; ++c)
          A[c] = __builtin_amdgcn_mfma_f32_16x16x32_bf16(wf0[c], h0f, z4, 0, 0, 0);
        #pragma unroll
        for (int c = 0; c < 8; ++c)
          A[c] = __builtin_amdgcn_mfma_f32_16x16x32_bf16(wf1[c], hf, A[c], 0, 0, 0);
        #pragma unroll
        for (int jj = 0; jj < 2; ++jj) {
          const float gi = SEL(A, 0, jj) + cx[0][jj];
          const float gf = SEL(A, 1, jj) + cx[1][jj];
          const float gg = SEL(A, 2, jj) + cx[2][jj];
          const float go = SEL(A, 3, jj) + cx[3][jj];
          const float iv = frcp(1.f + fexp2(gi));
          const float fv = frcp(1.f + fexp2(gf));
          const float gv = fmaf(frcp(1.f + fexp2(gg)), -2.f, 1.f);
          const float ov = frcp(1.f + fexp2(go));
          cv[jj] = fmaf(fv, cv[jj], iv * gv);
          const float th = fmaf(frcp(1.f + fexp2(cv[jj] * (2.f * L2E))), -2.f, 1.f);
          const float hn = ov * th;
          if (jj == 0) hn0 = hn; else hn1 = hn;
        }
        int pk;
        asm("v_cvt_pk_bf16_f32 %0, %1, %2" : "=v"(pk) : "v"(hn0), "v"(hn1));
        i32x4 hd1;
        hd1[0] = __builtin_amdgcn_ds_swizzle(pk, 0x013);
        hd1[1] = __builtin_amdgcn_ds_swizzle(pk, 0x093);
        hd1[2] = __builtin_amdgcn_ds_swizzle(pk, 0x113);
        hd1[3] = __builtin_amdgcn_ds_swizzle(pk, 0x193);
        hf = __builtin_bit_cast(bf16x8, hd1);
      }
    }
  }

  // ---- FC + ReLU (wave 1 holds h1(T-1) in hn0/hn1) ----
  if (w == 1) {
    float part = hn0 * wfcA + hn1 * wfcB;
    part += __shfl_xor(part, 4);
    part += __shfl_xor(part, 8);
    part += __shfl_xor(part, 16);
    part += __shfl_xor(part, 32);
    if (l < 4) {
      const float o = part + bfc[0];
      out[blockIdx.x * NBW + l] = o > 0.f ? o : 0.f;
    }
  }
}

extern "C" void kernel_launch(void* const* d_in, const int* in_sizes, int n_in,
                              void* d_out, int out_size, void* d_ws, size_t ws_size,
                              hipStream_t stream) {
  const float* x    = (const float*)d_in[0];
  const float* Wih0 = (const float*)d_in[1];
  const float* Whh0 = (const float*)d_in[2];
  const float* bih0 = (const float*)d_in[3];
  const float* bhh0 = (const float*)d_in[4];
  const float* Wih1 = (const float*)d_in[5];
  const float* Whh1 = (const float*)d_in[6];
  const float* bih1 = (const float*)d_in[7];
  const float* bhh1 = (const float*)d_in[8];
  const float* Wfc  = (const float*)d_in[9];
  const float* bfc  = (const float*)d_in[10];

  const int B = 4096;
  const int grid = B / NBW;   // 1024 blocks x 2 waves -> 2 waves/SIMD
  lstm2_pipe_kernel<<<grid, 128, 0, stream>>>(
      x, Wih0, Whh0, bih0, bhh0, Wih1, Whh1, bih1, bhh1, Wfc, bfc,
      (float*)d_out);
}

// Round 5
// 281.789 us; speedup vs baseline: 1.4392x; 1.0777x over previous
//
#include <hip/hip_runtime.h>
#include <hip/hip_bf16.h>

// 2-layer LSTM (H=32, T=512, I=1) + FC(1) + ReLU, fused, layer-pipelined at
// t4 granularity. Block = 128 threads = 2 waves: wave 0 runs layer 0, wave 1
// runs layer 1 FOUR steps behind; h0 handed over as ready B-fragments via a
// double-buffered LDS set of 4 (one __syncthreads per 4 steps). Per-wave
// structure: MFMA 16x16x32 bf16, NBW=4; lane (m,q,s) owns units 8m+2q+{0,1}
// of batch s; 3-cndmask gate select; cvt_pk + 4 ds_swizzle h reassembly.
// Wave 1 prefetches all 4 fragments and issues recurrent MFMA first.
// Activation scales pre-folded into weights; MFMA C-in = const zero.

typedef __attribute__((ext_vector_type(8))) short bf16x8;
typedef __attribute__((ext_vector_type(4))) float f32x4;
typedef __attribute__((ext_vector_type(4))) int   i32x4;

#define HID 32
#define SEQ 512
#define NT4 (SEQ / 4)
#define NBW 4
#define L2E 1.4426950408889634f

static __device__ __forceinline__ float fexp2(float x){ return __builtin_amdgcn_exp2f(x); }
static __device__ __forceinline__ float frcp (float x){ return __builtin_amdgcn_rcpf(x); }
static __device__ __forceinline__ short f2bf(float f){
  unsigned u = __builtin_bit_cast(unsigned, f);
  u = (u + 0x7fffu + ((u >> 16) & 1u)) >> 16;
  return (short)u;
}

// gate (tau, unit 8m+2q+jj) lives at A[2*tau + (q>>1)][2*(q&1) + jj]
#define SEL(Atab, tau, jj) \
  ( khb ? ( rb ? Atab[2*(tau)+1][2+(jj)] : Atab[2*(tau)+1][(jj)] ) \
        : ( rb ? Atab[2*(tau)  ][2+(jj)] : Atab[2*(tau)  ][(jj)] ) )

__global__ __launch_bounds__(128, 2) void lstm2_pipe4_kernel(
    const float* __restrict__ x,
    const float* __restrict__ Wih0, const float* __restrict__ Whh0,
    const float* __restrict__ bih0, const float* __restrict__ bhh0,
    const float* __restrict__ Wih1, const float* __restrict__ Whh1,
    const float* __restrict__ bih1, const float* __restrict__ bhh1,
    const float* __restrict__ Wfc, const float* __restrict__ bfc,
    float* __restrict__ out)
{
  const int tid = threadIdx.x;
  const int w   = tid >> 6;        // 0: layer-0 producer, 1: layer-1 consumer
  const int l   = tid & 63;
  const int m   = l >> 4;          // A/B fragment k-group
  const int col = l & 15;          // MFMA N col
  const int q   = col >> 2;        // replication group -> units 8m+2q+{0,1}
  const int s   = col & 3;         // batch slot
  const int batch = blockIdx.x * NBW + s;
  const bool khb = ((q >> 1) & 1) != 0;
  const bool rb  = (q & 1) != 0;

  __shared__ i32x4 hbuf[2][4][64];   // double-buffered 4-step h0 B-frags, 8 KiB

  // ---- weight fragments (A operands), rows pre-scaled by activation scale:
  //      i,f,o rows: -log2e (sigmoid);  g rows: +2*log2e (tanh)
  bf16x8 wf0[8], wf1[8];   // w==0: wf0=Whh0; w==1: wf0=Wih1, wf1=Whh1
  #pragma unroll
  for (int c = 0; c < 8; ++c) {
    const int tau = c >> 1, kh = c & 1;
    const float sc = (tau == 2) ? (2.0f * L2E) : (-L2E);
    const int ga = tau * 32 + (q << 3) + (kh << 2) + s;   // A-row = col packing
    if (w == 0) {
      #pragma unroll
      for (int j = 0; j < 8; ++j)
        wf0[c][j] = f2bf(sc * Whh0[ga * HID + (m * 8 + j)]);
    } else {
      #pragma unroll
      for (int j = 0; j < 8; ++j) {
        wf0[c][j] = f2bf(sc * Wih1[ga * HID + (m * 8 + j)]);
        wf1[c][j] = f2bf(sc * Whh1[ga * HID + (m * 8 + j)]);
      }
    }
  }

  // ---- per-lane activation constants for units u = 8m+2q+jj
  float cx[4][2], wx[4][2];
  #pragma unroll
  for (int tau = 0; tau < 4; ++tau) {
    const float sc = (tau == 2) ? (2.0f * L2E) : (-L2E);
    #pragma unroll
    for (int jj = 0; jj < 2; ++jj) {
      const int g = tau * 32 + 8 * m + 2 * q + jj;
      if (w == 0) {
        cx[tau][jj] = sc * (bih0[g] + bhh0[g]);
        wx[tau][jj] = sc * Wih0[g];
      } else {
        cx[tau][jj] = sc * (bih1[g] + bhh1[g]);
        wx[tau][jj] = 0.f;
      }
    }
  }
  float wfcA = 0.f, wfcB = 0.f;
  if (w == 1) { wfcA = Wfc[8 * m + 2 * q]; wfcB = Wfc[8 * m + 2 * q + 1]; }

  const f32x4 z4 = {0.f, 0.f, 0.f, 0.f};
  bf16x8 hf = {};                 // w0: own h0 frag; w1: own h1 frag
  float cv[2] = {0.f, 0.f};
  float hn0 = 0.f, hn1 = 0.f;

  const float* xb = x + (size_t)batch * SEQ;

  for (int k = 0; k <= NT4; ++k) {
    if (w == 0 && k < NT4) {
      // ---------- producer: 4 steps of layer 0 into set k&1 ----------
      const float4 xv = *reinterpret_cast<const float4*>(xb + k * 4);
      #pragma unroll
      for (int uu = 0; uu < 4; ++uu) {
        const float xt = (uu == 0) ? xv.x : (uu == 1) ? xv.y : (uu == 2) ? xv.z : xv.w;
        f32x4 A[8];
        #pragma unroll
        for (int c = 0; c < 8; ++c)
          A[c] = __builtin_amdgcn_mfma_f32_16x16x32_bf16(wf0[c], hf, z4, 0, 0, 0);
        #pragma unroll
        for (int jj = 0; jj < 2; ++jj) {
          const float gi = SEL(A, 0, jj) + fmaf(wx[0][jj], xt, cx[0][jj]);
          const float gf = SEL(A, 1, jj) + fmaf(wx[1][jj], xt, cx[1][jj]);
          const float gg = SEL(A, 2, jj) + fmaf(wx[2][jj], xt, cx[2][jj]);
          const float go = SEL(A, 3, jj) + fmaf(wx[3][jj], xt, cx[3][jj]);
          const float iv = frcp(1.f + fexp2(gi));                   // sigmoid
          const float fv = frcp(1.f + fexp2(gf));
          const float gv = fmaf(frcp(1.f + fexp2(gg)), -2.f, 1.f);  // tanh
          const float ov = frcp(1.f + fexp2(go));
          cv[jj] = fmaf(fv, cv[jj], iv * gv);
          const float th = fmaf(frcp(1.f + fexp2(cv[jj] * (2.f * L2E))), -2.f, 1.f);
          const float hn = ov * th;
          if (jj == 0) hn0 = hn; else hn1 = hn;
        }
        int pk;
        asm("v_cvt_pk_bf16_f32 %0, %1, %2" : "=v"(pk) : "v"(hn0), "v"(hn1));
        i32x4 hd;
        hd[0] = __builtin_amdgcn_ds_swizzle(pk, 0x013);
        hd[1] = __builtin_amdgcn_ds_swizzle(pk, 0x093);
        hd[2] = __builtin_amdgcn_ds_swizzle(pk, 0x113);
        hd[3] = __builtin_amdgcn_ds_swizzle(pk, 0x193);
        hf = __builtin_bit_cast(bf16x8, hd);
        hbuf[k & 1][uu][l] = hd;       // publish B-fragment for wave 1
      }
    }
    if (w == 1 && k > 0) {
      // ---------- consumer: 4 steps of layer 1 from set (k-1)&1 ----------
      i32x4 hd[4];
      #pragma unroll
      for (int uu = 0; uu < 4; ++uu) hd[uu] = hbuf[(k - 1) & 1][uu][l];
      #pragma unroll
      for (int uu = 0; uu < 4; ++uu) {
        const bf16x8 h0f = __builtin_bit_cast(bf16x8, hd[uu]);
        f32x4 A[8];
        #pragma unroll
        for (int c = 0; c < 8; ++c)   // recurrent (register-only) MFMA first
          A[c] = __builtin_amdgcn_mfma_f32_16x16x32_bf16(wf1[c], hf, z4, 0, 0, 0);
        #pragma unroll
        for (int c = 0; c < 8; ++c)   // LDS-dependent MFMA second
          A[c] = __builtin_amdgcn_mfma_f32_16x16x32_bf16(wf0[c], h0f, A[c], 0, 0, 0);
        #pragma unroll
        for (int jj = 0; jj < 2; ++jj) {
          const float gi = SEL(A, 0, jj) + cx[0][jj];
          const float gf = SEL(A, 1, jj) + cx[1][jj];
          const float gg = SEL(A, 2, jj) + cx[2][jj];
          const float go = SEL(A, 3, jj) + cx[3][jj];
          const float iv = frcp(1.f + fexp2(gi));
          const float fv = frcp(1.f + fexp2(gf));
          const float gv = fmaf(frcp(1.f + fexp2(gg)), -2.f, 1.f);
          const float ov = frcp(1.f + fexp2(go));
          cv[jj] = fmaf(fv, cv[jj], iv * gv);
          const float th = fmaf(frcp(1.f + fexp2(cv[jj] * (2.f * L2E))), -2.f, 1.f);
          const float hn = ov * th;
          if (jj == 0) hn0 = hn; else hn1 = hn;
        }
        int pk;
        asm("v_cvt_pk_bf16_f32 %0, %1, %2" : "=v"(pk) : "v"(hn0), "v"(hn1));
        i32x4 hd1;
        hd1[0] = __builtin_amdgcn_ds_swizzle(pk, 0x013);
        hd1[1] = __builtin_amdgcn_ds_swizzle(pk, 0x093);
        hd1[2] = __builtin_amdgcn_ds_swizzle(pk, 0x113);
        hd1[3] = __builtin_amdgcn_ds_swizzle(pk, 0x193);
        hf = __builtin_bit_cast(bf16x8, hd1);
      }
    }
    __syncthreads();
  }

  // ---- FC + ReLU (wave 1 holds h1(T-1) in hn0/hn1) ----
  if (w == 1) {
    float part = hn0 * wfcA + hn1 * wfcB;
    part += __shfl_xor(part, 4);
    part += __shfl_xor(part, 8);
    part += __shfl_xor(part, 16);
    part += __shfl_xor(part, 32);
    if (l < 4) {
      const float o = part + bfc[0];
      out[blockIdx.x * NBW + l] = o > 0.f ? o : 0.f;
    }
  }
}

extern "C" void kernel_launch(void* const* d_in, const int* in_sizes, int n_in,
                              void* d_out, int out_size, void* d_ws, size_t ws_size,
                              hipStream_t stream) {
  const float* x    = (const float*)d_in[0];
  const float* Wih0 = (const float*)d_in[1];
  const float* Whh0 = (const float*)d_in[2];
  const float* bih0 = (const float*)d_in[3];
  const float* bhh0 = (const float*)d_in[4];
  const float* Wih1 = (const float*)d_in[5];
  const float* Whh1 = (const float*)d_in[6];
  const float* bih1 = (const float*)d_in[7];
  const float* bhh1 = (const float*)d_in[8];
  const float* Wfc  = (const float*)d_in[9];
  const float* bfc  = (const float*)d_in[10];

  const int B = 4096;
  const int grid = B / NBW;   // 1024 blocks x 2 waves -> 2 waves/SIMD
  lstm2_pipe4_kernel<<<grid, 128, 0, stream>>>(
      x, Wih0, Whh0, bih0, bhh0, Wih1, Whh1, bih1, bhh1, Wfc, bfc,
      (float*)d_out);
}